// Round 3
// baseline (145.055 us; speedup 1.0000x reference)
//
#include <hip/hip_runtime.h>
#include <cstdint>
#include <cstddef>

typedef __bf16 bf16_t;
typedef __bf16 bf16x4 __attribute__((ext_vector_type(4)));
typedef __bf16 bf16x8 __attribute__((ext_vector_type(8)));
typedef float f32x4 __attribute__((ext_vector_type(4)));

__device__ __forceinline__ void gload_lds16(const bf16_t* g, bf16_t* l) {
  __builtin_amdgcn_global_load_lds((const __attribute__((address_space(1))) void*)g,
                                   (__attribute__((address_space(3))) void*)l,
                                   16, 0, 0);
}

__device__ __forceinline__ f32x4 mfma16(bf16x8 a, bf16x8 b, f32x4 c) {
  return __builtin_amdgcn_mfma_f32_16x16x32_bf16(a, b, c, 0, 0, 0);
}

// ---------------- fused prep: patchify + weight transpose + pe + mask bias ----------------
__global__ __launch_bounds__(256)
void prep_all(const float* __restrict__ img0, const float* __restrict__ img1,
              const float* __restrict__ mask,
              const float* __restrict__ wp, const float* __restrict__ wkv,
              const float* __restrict__ wqv, const float* __restrict__ wfc1,
              const float* __restrict__ wfc2,
              bf16_t* __restrict__ xp0, bf16_t* __restrict__ xp1,
              float* __restrict__ pe, float* __restrict__ bias,
              bf16_t* __restrict__ wpT, bf16_t* __restrict__ wkvT,
              bf16_t* __restrict__ wqT, bf16_t* __restrict__ wfc1T,
              bf16_t* __restrict__ wfc2T) {
  int bid = blockIdx.x, tid = threadIdx.x;
  if (bid < 1536) {
    int imgsel = bid >= 768;
    int t = (bid - (imgsel ? 768 : 0)) * 256 + tid;
    const float* img = imgsel ? img1 : img0;
    bf16_t* xp = imgsel ? xp1 : xp0;
    int wpp = t & 31, p1 = (t >> 5) & 7, hp = (t >> 8) & 31, rest = t >> 13;
    int b = rest / 3, c = rest - b * 3;
    const float* src = img + (((size_t)(b * 3 + c) * 256 + hp * 8 + p1) * 256 + wpp * 8);
    float4 v0 = *(const float4*)src;
    float4 v1 = *(const float4*)(src + 4);
    int row = b * 1024 + hp * 32 + wpp;
    bf16_t* dst = xp + (size_t)row * 192 + p1 * 24 + c;
    dst[0]  = (bf16_t)v0.x; dst[3]  = (bf16_t)v0.y; dst[6]  = (bf16_t)v0.z; dst[9]  = (bf16_t)v0.w;
    dst[12] = (bf16_t)v1.x; dst[15] = (bf16_t)v1.y; dst[18] = (bf16_t)v1.z; dst[21] = (bf16_t)v1.w;
  } else if (bid < 4544) {
    int g = (bid - 1536) * 256 + tid;
    if (g < 49152) {                       // wpT [256][192]
      int idx = g; int n = idx / 192, k = idx - n * 192;
      wpT[idx] = (bf16_t)wp[k * 256 + n];
    } else if (g < 180224) {               // wkvT [512][256]
      int idx = g - 49152; int n = idx >> 8, k = idx & 255;
      wkvT[idx] = (bf16_t)wkv[k * 512 + n];
    } else if (g < 245760) {               // wqT [256][256]
      int idx = g - 180224; int n = idx >> 8, k = idx & 255;
      wqT[idx] = (bf16_t)wqv[k * 512 + n];
    } else if (g < 507904) {               // wfc1T [1024][256]
      int idx = g - 245760; int n = idx >> 8, k = idx & 255;
      wfc1T[idx] = (bf16_t)wfc1[k * 1024 + n];
    } else if (g < 770048) {               // wfc2T [256(pad)][1024]
      int idx = g - 507904; int n = idx >> 10, k = idx & 1023;
      wfc2T[idx] = (n < 192) ? (bf16_t)wfc2[k * 192 + n] : (bf16_t)0.0f;
    }
  } else if (bid < 5568) {
    int t = bid - 4544, c = tid;
    int i2 = c & ~1;
    float div = expf((float)i2 * (-9.210340371976184f / 256.0f));
    float arg = (float)t * div;
    pe[t * 256 + c] = (c & 1) ? cosf(arg) : sinf(arg);
  } else {
    int g = (bid - 5568) * 256 + tid;   // 8192
    int b = g >> 10, t = g & 1023, hp = t >> 5, wpp = t & 31;
    const float* mp = mask + ((size_t)b * 256 + hp * 8) * 256 + wpp * 8;
    float s = 0.f;
    #pragma unroll
    for (int p1 = 0; p1 < 8; p1++) {
      float4 a = *(const float4*)(mp + p1 * 256);
      float4 c = *(const float4*)(mp + p1 * 256 + 4);
      s += a.x + a.y + a.z + a.w + c.x + c.y + c.z + c.w;
    }
    bias[g] = (s > 0.f) ? 0.f : -100.f;
  }
}

// ---------------- generic GEMM: C = A(MxK) * Bt(NxK)^T ----------------
// EPI 0: patch embed (+bias+pe -> bf16), blockIdx.z picks (A,out_b) vs (A2,out_b2)
// EPI 5: fused kv+q (BN=128): y<4 -> kv from A; y>=4 -> q from A2 -> out_b3
// EPI 3: +bias, GELU -> bf16
// EPI 4: +bias -> f32 unpatchify out
template<int EPI, int BN>
__global__ __launch_bounds__(256)
void gemm_bt(const bf16_t* __restrict__ A_, const bf16_t* __restrict__ A2,
             const bf16_t* __restrict__ Bt_, const bf16_t* __restrict__ Bt2,
             int M, int N, int K,
             const float* __restrict__ bias_, const float* __restrict__ bias2,
             const float* __restrict__ pe,
             bf16_t* __restrict__ out_b, bf16_t* __restrict__ out_b2,
             bf16_t* __restrict__ out_b3, float* __restrict__ out_f) {
  constexpr int NF = BN / 32;            // 16-wide col frags per wave
  __shared__ bf16_t alds[4 * 64 * 8];    // [kblk][row][8]
  __shared__ bf16_t blds[4 * BN * 8];
  const int tid = threadIdx.x;
  const int lane = tid & 63, wid = tid >> 6;
  const int ln15 = lane & 15, hi = lane >> 4;
  const int brow = blockIdx.x * 64;
  int bcol = blockIdx.y * BN;
  const bf16_t* A = A_;
  const bf16_t* Bt = Bt_;
  const float* bias = bias_;
  bool qpart = false;
  if (EPI == 0 && blockIdx.z) A = A2;
  if (EPI == 5 && blockIdx.y >= 4) {
    qpart = true; A = A2; Bt = Bt2; bias = bias2; bcol -= 512;
  }
  const int wr = wid >> 1, wc = wid & 1;

  f32x4 acc[2][NF];
  #pragma unroll
  for (int m = 0; m < 2; m++)
    #pragma unroll
    for (int n = 0; n < NF; n++) acc[m][n] = (f32x4){0.f, 0.f, 0.f, 0.f};

  for (int k0 = 0; k0 < K; k0 += 32) {
    {  // stage A tile 64x32, layout [kblk][64][8]
      int c = tid; int row = c & 63; int kb = c >> 6;
      const bf16_t* g = A + (size_t)(brow + row) * K + k0 + kb * 8;
      gload_lds16(g, &alds[(wid * 64) * 8]);
    }
    #pragma unroll
    for (int s = 0; s < BN / 64; s++) {  // stage B tile BNx32
      int c = tid + s * 256; int row = c & (BN - 1); int kb = c / BN;
      const bf16_t* g = Bt + (size_t)(bcol + row) * K + k0 + kb * 8;
      gload_lds16(g, &blds[(wid * 64 + s * 256) * 8]);
    }
    __syncthreads();
    bf16x8 af[2], bfr[NF];
    #pragma unroll
    for (int m = 0; m < 2; m++)
      af[m] = *(const bf16x8*)&alds[(hi * 64 + wr * 32 + m * 16 + ln15) * 8];
    #pragma unroll
    for (int n = 0; n < NF; n++)
      bfr[n] = *(const bf16x8*)&blds[(hi * BN + wc * (BN / 2) + n * 16 + ln15) * 8];
    #pragma unroll
    for (int m = 0; m < 2; m++)
      #pragma unroll
      for (int n = 0; n < NF; n++)
        acc[m][n] = mfma16(af[m], bfr[n], acc[m][n]);
    __syncthreads();
  }

  #pragma unroll
  for (int m = 0; m < 2; m++) {
    #pragma unroll
    for (int n = 0; n < NF; n++) {
      #pragma unroll
      for (int r = 0; r < 4; r++) {
        int grow = brow + wr * 32 + m * 16 + hi * 4 + r;
        int gcol = bcol + wc * (BN / 2) + n * 16 + ln15;
        float v = acc[m][n][r];
        if (EPI == 0) {
          v += bias[gcol] + pe[(grow & 1023) * 256 + gcol];
          bf16_t* outx = blockIdx.z ? out_b2 : out_b;
          outx[(size_t)grow * N + gcol] = (bf16_t)v;
        } else if (EPI == 5) {
          v += bias[gcol];
          int b = grow >> 10, t = grow & 1023;
          if (!qpart) {
            if (gcol < 256) {
              int h = gcol >> 5, d = gcol & 31;
              out_b[(((size_t)(b * 8 + h) * 1024 + t) << 5) + d] = (bf16_t)v;
            } else {
              int c2 = gcol - 256; int h = c2 >> 5, d = c2 & 31;
              out_b2[(((size_t)(b * 8 + h) * 32 + d) << 10) + t] = (bf16_t)v;
            }
          } else {
            v *= 0.17677669529663687f;   // 1/sqrt(32)
            int h = gcol >> 5, d = gcol & 31;
            out_b3[(((size_t)(b * 8 + h) * 1024 + t) << 5) + d] = (bf16_t)v;
          }
        } else if (EPI == 3) {
          v += bias[gcol];
          float gg = 0.5f * v * (1.0f + erff(v * 0.7071067811865476f));
          out_b[(size_t)grow * N + gcol] = (bf16_t)gg;
        } else if (EPI == 4) {
          if (gcol < 192) {
            v += bias[gcol];
            int b = grow >> 10, t = grow & 1023;
            int hp = t >> 5, wpp = t & 31;
            int p = gcol / 3; int c = gcol - p * 3;
            int p1 = p >> 3, p2 = p & 7;
            out_f[(((size_t)(b * 3 + c) * 256 + hp * 8 + p1) * 256) + wpp * 8 + p2] = v;
          }
        }
      }
    }
  }
}

// ---------------- attention helpers ----------------
__device__ __forceinline__ void attn_load(int kt, const bf16_t* kbase, const bf16_t* vbase,
                                          const float* bb, int ln15, int hi,
                                          bf16x8& kf0, bf16x8& kf1, bf16x8& vf0, bf16x8& vf1,
                                          f32x4& ba0, f32x4& ba1) {
  int k0 = kt * 32;
  kf0 = *(const bf16x8*)(kbase + (size_t)(k0 + ln15) * 32 + hi * 8);
  kf1 = *(const bf16x8*)(kbase + (size_t)(k0 + 16 + ln15) * 32 + hi * 8);
  vf0 = *(const bf16x8*)(vbase + (size_t)ln15 * 1024 + k0 + hi * 8);
  vf1 = *(const bf16x8*)(vbase + (size_t)(16 + ln15) * 1024 + k0 + hi * 8);
  ba0 = *(const f32x4*)(bb + k0 + hi * 4);
  ba1 = *(const f32x4*)(bb + k0 + 16 + hi * 4);
}

__device__ __forceinline__ void attn_step(bf16x8 kf0, bf16x8 kf1, bf16x8 vf0, bf16x8 vf1,
                                          f32x4 ba0, f32x4 ba1, bf16x8 qf,
                                          char* pwb, int ln15, int hi,
                                          float& lsum, f32x4& o0, f32x4& o1) {
  // S^T = K·Q^T + bias: lane holds S^T[key=hi*4+r][q=ln15] per 16-key chunk
  f32x4 s0 = mfma16(kf0, qf, ba0);
  f32x4 s1 = mfma16(kf1, qf, ba1);
  float e0 = __expf(s0[0]), e1 = __expf(s0[1]), e2 = __expf(s0[2]), e3 = __expf(s0[3]);
  float f0 = __expf(s1[0]), f1 = __expf(s1[1]), f2 = __expf(s1[2]), f3 = __expf(s1[3]);
  lsum += ((e0 + e1) + (e2 + e3)) + ((f0 + f1) + (f2 + f3));
  bf16x4 pk0, pk1;
  pk0[0] = (bf16_t)e0; pk0[1] = (bf16_t)e1; pk0[2] = (bf16_t)e2; pk0[3] = (bf16_t)e3;
  pk1[0] = (bf16_t)f0; pk1[1] = (bf16_t)f1; pk1[2] = (bf16_t)f2; pk1[3] = (bf16_t)f3;
  // P layout [q=ln15][32 k], row stride 80B; k-pos chunk0: hi*4, chunk1: 16+hi*4
  *(bf16x4*)(pwb + ln15 * 80 + hi * 8) = pk0;
  *(bf16x4*)(pwb + ln15 * 80 + 32 + hi * 8) = pk1;
  bf16x8 pf = *(const bf16x8*)(pwb + ln15 * 80 + hi * 16);  // A-frag: P[q=ln15][k=hi*8+i]
  o0 = mfma16(pf, vf0, o0);
  o1 = mfma16(pf, vf1, o1);
}

// ---------------- fused attention, no-max softmax, prefetched ----------------
__global__ __launch_bounds__(256)
void attn_kernel(const bf16_t* __restrict__ q, const bf16_t* __restrict__ k,
                 const bf16_t* __restrict__ vt, const float* __restrict__ bias,
                 bf16_t* __restrict__ out) {
  __shared__ bf16_t plds[4 * 16 * 40];   // per wave: [16 q][40] (80B row stride)
  int tid = threadIdx.x;
  int lane = tid & 63, wid = tid >> 6, ln15 = lane & 15, hi = lane >> 4;
  // XCD swizzle: all 16 q-blocks of one (b,h) on one XCD (K/V L2 locality)
  int x = blockIdx.x & 7, idx = blockIdx.x >> 3;
  int qb = idx & 15;
  int bh = ((idx >> 4) << 3) | x;
  int b = bh >> 3, h = bh & 7;
  int qrow = qb * 64 + wid * 16 + ln15;
  bf16x8 qf = *(const bf16x8*)(q + ((size_t)bh * 1024 + qrow) * 32 + hi * 8);
  const bf16_t* kbase = k + (size_t)bh * 32768;
  const bf16_t* vbase = vt + (size_t)bh * 32768;
  const float* bb = bias + b * 1024;
  char* pwb = (char*)&plds[wid * 640];

  float lsum = 0.f;
  f32x4 o0 = (f32x4){0.f, 0.f, 0.f, 0.f}, o1 = o0;

  bf16x8 ka0, ka1, va0, va1, kb0, kb1, vb0, vb1;
  f32x4 aa0, aa1, ab0, ab1;
  attn_load(0, kbase, vbase, bb, ln15, hi, ka0, ka1, va0, va1, aa0, aa1);
  for (int kt = 0; kt < 32; kt += 2) {
    attn_load(kt + 1, kbase, vbase, bb, ln15, hi, kb0, kb1, vb0, vb1, ab0, ab1);
    attn_step(ka0, ka1, va0, va1, aa0, aa1, qf, pwb, ln15, hi, lsum, o0, o1);
    int ktn = (kt + 2 < 32) ? kt + 2 : 31;   // clamped redundant tail load
    attn_load(ktn, kbase, vbase, bb, ln15, hi, ka0, ka1, va0, va1, aa0, aa1);
    attn_step(kb0, kb1, vb0, vb1, ab0, ab1, qf, pwb, ln15, hi, lsum, o0, o1);
  }

  lsum += __shfl_xor(lsum, 16);
  lsum += __shfl_xor(lsum, 32);          // all lanes: l for q=ln15
  #pragma unroll
  for (int r = 0; r < 4; r++) {
    float linv = 1.f / __shfl(lsum, hi * 4 + r);   // l for q-row hi*4+r
    int qg = qb * 64 + wid * 16 + hi * 4 + r;
    size_t rowbase = ((size_t)b * 1024 + qg) * 256 + h * 32;
    out[rowbase + ln15] = (bf16_t)(o0[r] * linv);
    out[rowbase + 16 + ln15] = (bf16_t)(o1[r] * linv);
  }
}

// ---------------- launch ----------------
extern "C" void kernel_launch(void* const* d_in, const int* in_sizes, int n_in,
                              void* d_out, int out_size, void* d_ws, size_t ws_size,
                              hipStream_t stream) {
  (void)in_sizes; (void)n_in; (void)out_size; (void)ws_size;
  const float* img0    = (const float*)d_in[0];
  const float* img1    = (const float*)d_in[1];
  const float* mask    = (const float*)d_in[2];
  const float* w_patch = (const float*)d_in[3];
  const float* b_patch = (const float*)d_in[4];
  const float* w_kv    = (const float*)d_in[5];
  const float* b_kv    = (const float*)d_in[6];
  const float* w_qv    = (const float*)d_in[7];
  const float* b_qv    = (const float*)d_in[8];
  const float* w_fc1   = (const float*)d_in[9];
  const float* b_fc1   = (const float*)d_in[10];
  const float* w_fc2   = (const float*)d_in[11];
  const float* b_fc2   = (const float*)d_in[12];
  float* out = (float*)d_out;

  char* ws = (char*)d_ws;
  float*  pe    = (float*)(ws + 0);
  float*  bias  = (float*)(ws + 1048576);
  bf16_t* wpT   = (bf16_t*)(ws + 1081344);
  bf16_t* wkvT  = (bf16_t*)(ws + 1179648);
  bf16_t* wqT   = (bf16_t*)(ws + 1441792);
  bf16_t* wfc1T = (bf16_t*)(ws + 1572864);
  bf16_t* wfc2T = (bf16_t*)(ws + 2097152);
  bf16_t* xp0   = (bf16_t*)(ws + 2621440);
  bf16_t* xp1   = (bf16_t*)(ws + 5767168);
  bf16_t* x0    = (bf16_t*)(ws + 8912896);
  bf16_t* x1    = (bf16_t*)(ws + 13107200);
  bf16_t* kbuf  = (bf16_t*)(ws + 17301504);
  bf16_t* vtbuf = (bf16_t*)(ws + 21495808);
  bf16_t* qbuf  = (bf16_t*)(ws + 25690112);
  bf16_t* aout  = (bf16_t*)(ws + 29884416);
  bf16_t* hbuf  = (bf16_t*)(ws + 34078720);

  prep_all<<<5600, 256, 0, stream>>>(img0, img1, mask, w_patch, w_kv, w_qv, w_fc1, w_fc2,
                                     xp0, xp1, pe, bias, wpT, wkvT, wqT, wfc1T, wfc2T);

  gemm_bt<0, 64><<<dim3(128, 4, 2), 256, 0, stream>>>(xp0, xp1, wpT, nullptr, 8192, 256, 192,
                                                      b_patch, nullptr, pe, x0, x1, nullptr, nullptr);
  gemm_bt<5, 128><<<dim3(128, 6), 256, 0, stream>>>(x0, x1, wkvT, wqT, 8192, 512, 256,
                                                    b_kv, b_qv, nullptr, kbuf, vtbuf, qbuf, nullptr);

  attn_kernel<<<1024, 256, 0, stream>>>(qbuf, kbuf, vtbuf, bias, aout);

  gemm_bt<3, 128><<<dim3(128, 8), 256, 0, stream>>>(aout, nullptr, wfc1T, nullptr, 8192, 1024, 256,
                                                    b_fc1, nullptr, nullptr, hbuf, nullptr, nullptr, nullptr);
  gemm_bt<4, 64><<<dim3(128, 4), 256, 0, stream>>>(hbuf, nullptr, wfc2T, nullptr, 8192, 256, 1024,
                                                   b_fc2, nullptr, nullptr, nullptr, nullptr, nullptr, out);
}

// Round 4
// 126.206 us; speedup vs baseline: 1.1494x; 1.1494x over previous
//
#include <hip/hip_runtime.h>
#include <cstdint>
#include <cstddef>

typedef __bf16 bf16_t;
typedef uint32_t u32;
typedef __bf16 bf16x4 __attribute__((ext_vector_type(4)));
typedef __bf16 bf16x8 __attribute__((ext_vector_type(8)));
typedef float f32x4 __attribute__((ext_vector_type(4)));
typedef float f32x16 __attribute__((ext_vector_type(16)));

__device__ __forceinline__ void gload_lds16(const bf16_t* g, bf16_t* l) {
  __builtin_amdgcn_global_load_lds((const __attribute__((address_space(1))) void*)g,
                                   (__attribute__((address_space(3))) void*)l,
                                   16, 0, 0);
}

__device__ __forceinline__ f32x4 mfma16(bf16x8 a, bf16x8 b, f32x4 c) {
  return __builtin_amdgcn_mfma_f32_16x16x32_bf16(a, b, c, 0, 0, 0);
}
__device__ __forceinline__ f32x16 mfma32(bf16x8 a, bf16x8 b, f32x16 c) {
  return __builtin_amdgcn_mfma_f32_32x32x16_bf16(a, b, c, 0, 0, 0);
}

#define LOG2E 1.4426950408889634f

// ---------------- fused prep ----------------
// grid 2772 x 256:
//   [0,1536)      patchify both images
//   [1536,2560)   pe [1024][256]
//   [2560,2592)   mask bias (log2 domain)
//   [2592,2772)   LDS-tiled weight transposes + wfc2T pad-zero
__global__ __launch_bounds__(256)
void prep_all(const float* __restrict__ img0, const float* __restrict__ img1,
              const float* __restrict__ mask,
              const float* __restrict__ wp, const float* __restrict__ wkv,
              const float* __restrict__ wqv, const float* __restrict__ wfc1,
              const float* __restrict__ wfc2,
              bf16_t* __restrict__ xp0, bf16_t* __restrict__ xp1,
              float* __restrict__ pe, float* __restrict__ bias,
              bf16_t* __restrict__ wpT, bf16_t* __restrict__ wkvT,
              bf16_t* __restrict__ wqT, bf16_t* __restrict__ wfc1T,
              bf16_t* __restrict__ wfc2T) {
  __shared__ float tl[64 * 65];
  int bid = blockIdx.x, tid = threadIdx.x;
  if (bid < 1536) {
    int imgsel = bid >= 768;
    int t = (bid - (imgsel ? 768 : 0)) * 256 + tid;
    const float* img = imgsel ? img1 : img0;
    bf16_t* xp = imgsel ? xp1 : xp0;
    int wpp = t & 31, p1 = (t >> 5) & 7, hp = (t >> 8) & 31, rest = t >> 13;
    int b = rest / 3, c = rest - b * 3;
    const float* src = img + (((size_t)(b * 3 + c) * 256 + hp * 8 + p1) * 256 + wpp * 8);
    float4 v0 = *(const float4*)src;
    float4 v1 = *(const float4*)(src + 4);
    int row = b * 1024 + hp * 32 + wpp;
    bf16_t* dst = xp + (size_t)row * 192 + p1 * 24 + c;
    dst[0]  = (bf16_t)v0.x; dst[3]  = (bf16_t)v0.y; dst[6]  = (bf16_t)v0.z; dst[9]  = (bf16_t)v0.w;
    dst[12] = (bf16_t)v1.x; dst[15] = (bf16_t)v1.y; dst[18] = (bf16_t)v1.z; dst[21] = (bf16_t)v1.w;
  } else if (bid < 2560) {
    int t = bid - 1536, c = tid;
    int i2 = c & ~1;
    float div = expf((float)i2 * (-9.210340371976184f / 256.0f));
    float arg = (float)t * div;
    pe[t * 256 + c] = (c & 1) ? cosf(arg) : sinf(arg);
  } else if (bid < 2592) {
    int g = (bid - 2560) * 256 + tid;   // 8192
    int b = g >> 10, t = g & 1023, hp = t >> 5, wpp = t & 31;
    const float* mp = mask + ((size_t)b * 256 + hp * 8) * 256 + wpp * 8;
    float s = 0.f;
    #pragma unroll
    for (int p1 = 0; p1 < 8; p1++) {
      float4 a = *(const float4*)(mp + p1 * 256);
      float4 c = *(const float4*)(mp + p1 * 256 + 4);
      s += a.x + a.y + a.z + a.w + c.x + c.y + c.z + c.w;
    }
    bias[g] = (s > 0.f) ? 0.f : (-100.f * LOG2E);   // log2-domain bias
  } else {
    int i = bid - 2592;
    const float* src; bf16_t* dst; int srcN, dstK, NT;
    if (i >= 172) {                  // zero-pad wfc2T rows 192..255
      int j = i - 172;               // 0..7, 8192 elems each
      bf16_t* p = wfc2T + 192 * 1024 + j * 8192 + tid * 32;
      bf16x8 z;
      #pragma unroll
      for (int e = 0; e < 8; e++) z[e] = (bf16_t)0.0f;
      *(bf16x8*)(p) = z; *(bf16x8*)(p + 8) = z;
      *(bf16x8*)(p + 16) = z; *(bf16x8*)(p + 24) = z;
      return;
    }
    if (i < 12)       { src = wp;   dst = wpT;   srcN = 256;  dstK = 192;  NT = 4; }
    else if (i < 44)  { i -= 12;  src = wkv;  dst = wkvT;  srcN = 512;  dstK = 256;  NT = 8; }
    else if (i < 60)  { i -= 44;  src = wqv;  dst = wqT;   srcN = 512;  dstK = 256;  NT = 4; }
    else if (i < 124) { i -= 60;  src = wfc1; dst = wfc1T; srcN = 1024; dstK = 256;  NT = 16; }
    else              { i -= 124; src = wfc2; dst = wfc2T; srcN = 192;  dstK = 1024; NT = 3; }
    int kt = i / NT, nt = i - kt * NT;
    // load 64x64 f32 tile coalesced
    #pragma unroll
    for (int j = 0; j < 4; j++) {
      int r = (tid >> 4) + 16 * j, c = (tid & 15) * 4;
      float4 v = *(const float4*)(src + (size_t)(kt * 64 + r) * srcN + nt * 64 + c);
      tl[r * 65 + c] = v.x; tl[r * 65 + c + 1] = v.y;
      tl[r * 65 + c + 2] = v.z; tl[r * 65 + c + 3] = v.w;
    }
    __syncthreads();
    // write transposed, coalesced
    #pragma unroll
    for (int j = 0; j < 16; j++) {
      int flat = tid + 256 * j;
      int n_l = flat >> 6, k_l = flat & 63;
      dst[(size_t)(nt * 64 + n_l) * dstK + kt * 64 + k_l] = (bf16_t)tl[k_l * 65 + n_l];
    }
  }
}

// ---------------- generic GEMM: C = A(MxK) * Bt(NxK)^T ----------------
// EPI 0: patch embed (+bias+pe -> bf16), blockIdx.z picks (A,out_b) vs (A2,out_b2)
// EPI 5: fused kv+q (BN=128): y<4 -> kv from A; y>=4 -> q from A2 -> out_b3 (log2e-scaled)
// EPI 3: +bias, GELU -> bf16
// EPI 4: +bias -> f32 unpatchify out
template<int EPI, int BN>
__global__ __launch_bounds__(256)
void gemm_bt(const bf16_t* __restrict__ A_, const bf16_t* __restrict__ A2,
             const bf16_t* __restrict__ Bt_, const bf16_t* __restrict__ Bt2,
             int M, int N, int K,
             const float* __restrict__ bias_, const float* __restrict__ bias2,
             const float* __restrict__ pe,
             bf16_t* __restrict__ out_b, bf16_t* __restrict__ out_b2,
             bf16_t* __restrict__ out_b3, float* __restrict__ out_f) {
  constexpr int NF = BN / 32;
  __shared__ bf16_t alds[4 * 64 * 8];
  __shared__ bf16_t blds[4 * BN * 8];
  const int tid = threadIdx.x;
  const int lane = tid & 63, wid = tid >> 6;
  const int ln15 = lane & 15, hi = lane >> 4;
  const int brow = blockIdx.x * 64;
  int bcol = blockIdx.y * BN;
  const bf16_t* A = A_;
  const bf16_t* Bt = Bt_;
  const float* bias = bias_;
  bool qpart = false;
  if (EPI == 0 && blockIdx.z) A = A2;
  if (EPI == 5 && blockIdx.y >= 4) {
    qpart = true; A = A2; Bt = Bt2; bias = bias2; bcol -= 512;
  }
  const int wr = wid >> 1, wc = wid & 1;

  f32x4 acc[2][NF];
  #pragma unroll
  for (int m = 0; m < 2; m++)
    #pragma unroll
    for (int n = 0; n < NF; n++) acc[m][n] = (f32x4){0.f, 0.f, 0.f, 0.f};

  for (int k0 = 0; k0 < K; k0 += 32) {
    {
      int c = tid; int row = c & 63; int kb = c >> 6;
      const bf16_t* g = A + (size_t)(brow + row) * K + k0 + kb * 8;
      gload_lds16(g, &alds[(wid * 64) * 8]);
    }
    #pragma unroll
    for (int s = 0; s < BN / 64; s++) {
      int c = tid + s * 256; int row = c & (BN - 1); int kb = c / BN;
      const bf16_t* g = Bt + (size_t)(bcol + row) * K + k0 + kb * 8;
      gload_lds16(g, &blds[(wid * 64 + s * 256) * 8]);
    }
    __syncthreads();
    bf16x8 af[2], bfr[NF];
    #pragma unroll
    for (int m = 0; m < 2; m++)
      af[m] = *(const bf16x8*)&alds[(hi * 64 + wr * 32 + m * 16 + ln15) * 8];
    #pragma unroll
    for (int n = 0; n < NF; n++)
      bfr[n] = *(const bf16x8*)&blds[(hi * BN + wc * (BN / 2) + n * 16 + ln15) * 8];
    #pragma unroll
    for (int m = 0; m < 2; m++)
      #pragma unroll
      for (int n = 0; n < NF; n++)
        acc[m][n] = mfma16(af[m], bfr[n], acc[m][n]);
    __syncthreads();
  }

  #pragma unroll
  for (int m = 0; m < 2; m++) {
    #pragma unroll
    for (int n = 0; n < NF; n++) {
      #pragma unroll
      for (int r = 0; r < 4; r++) {
        int grow = brow + wr * 32 + m * 16 + hi * 4 + r;
        int gcol = bcol + wc * (BN / 2) + n * 16 + ln15;
        float v = acc[m][n][r];
        if (EPI == 0) {
          v += bias[gcol] + pe[(grow & 1023) * 256 + gcol];
          bf16_t* outx = blockIdx.z ? out_b2 : out_b;
          outx[(size_t)grow * N + gcol] = (bf16_t)v;
        } else if (EPI == 5) {
          v += bias[gcol];
          int b = grow >> 10, t = grow & 1023;
          if (!qpart) {
            if (gcol < 256) {
              int h = gcol >> 5, d = gcol & 31;
              out_b[(((size_t)(b * 8 + h) * 1024 + t) << 5) + d] = (bf16_t)v;
            } else {
              int c2 = gcol - 256; int h = c2 >> 5, d = c2 & 31;
              out_b2[(((size_t)(b * 8 + h) * 32 + d) << 10) + t] = (bf16_t)v;
            }
          } else {
            v *= (0.17677669529663687f * LOG2E);   // 1/sqrt(32) * log2(e)
            int h = gcol >> 5, d = gcol & 31;
            out_b3[(((size_t)(b * 8 + h) * 1024 + t) << 5) + d] = (bf16_t)v;
          }
        } else if (EPI == 3) {
          v += bias[gcol];
          float gg = 0.5f * v * (1.0f + erff(v * 0.7071067811865476f));
          out_b[(size_t)grow * N + gcol] = (bf16_t)gg;
        } else if (EPI == 4) {
          if (gcol < 192) {
            v += bias[gcol];
            int b = grow >> 10, t = grow & 1023;
            int hp = t >> 5, wpp = t & 31;
            int p = gcol / 3; int c = gcol - p * 3;
            int p1 = p >> 3, p2 = p & 7;
            out_f[(((size_t)(b * 3 + c) * 256 + hp * 8 + p1) * 256) + wpp * 8 + p2] = v;
          }
        }
      }
    }
  }
}

// ---------------- attention: 32x32 MFMA, in-register P, no LDS ----------------
struct Ld { bf16x8 kA, kB, vA, vB; f32x4 c0, c1, c2, c3; };

__device__ __forceinline__ void ldstep(int k0, const bf16_t* kb, const bf16_t* vb,
                                       const float* bb, int l31, int g, Ld& L) {
  L.kA = *(const bf16x8*)(kb + (size_t)(k0 + l31) * 32 + g * 8);
  L.kB = *(const bf16x8*)(kb + (size_t)(k0 + l31) * 32 + 16 + g * 8);
  L.vA = *(const bf16x8*)(vb + (size_t)l31 * 1024 + k0 + g * 8);
  L.vB = *(const bf16x8*)(vb + (size_t)l31 * 1024 + k0 + 16 + g * 8);
  L.c0 = *(const f32x4*)(bb + k0 + 4 * g);
  L.c1 = *(const f32x4*)(bb + k0 + 8 + 4 * g);
  L.c2 = *(const f32x4*)(bb + k0 + 16 + 4 * g);
  L.c3 = *(const f32x4*)(bb + k0 + 24 + 4 * g);
}

union PW { u32 w[4]; bf16x8 v; };

__device__ __forceinline__ u32 pkbf(float a, float b) {
  union { bf16_t h[2]; u32 w; } u;
  u.h[0] = (bf16_t)a; u.h[1] = (bf16_t)b;
  return u.w;
}

__device__ __forceinline__ void step(const Ld& L, bf16x8 qf0, bf16x8 qf1, int g,
                                     f32x16& acc, f32x16& lacc, bf16x8 onesb) {
  f32x16 S;
  S[0] = L.c0[0]; S[1] = L.c0[1]; S[2] = L.c0[2]; S[3] = L.c0[3];
  S[4] = L.c1[0]; S[5] = L.c1[1]; S[6] = L.c1[2]; S[7] = L.c1[3];
  S[8] = L.c2[0]; S[9] = L.c2[1]; S[10] = L.c2[2]; S[11] = L.c2[3];
  S[12] = L.c3[0]; S[13] = L.c3[1]; S[14] = L.c3[2]; S[15] = L.c3[3];
  S = mfma32(L.kA, qf0, S);            // S^T[key][q], log2 domain, bias pre-added
  S = mfma32(L.kB, qf1, S);
  float p[16];
  #pragma unroll
  for (int r = 0; r < 16; r++) p[r] = exp2f(S[r]);
  u32 w[8];
  #pragma unroll
  for (int j = 0; j < 8; j++) w[j] = pkbf(p[2 * j], p[2 * j + 1]);
  // cross-half exchange: g=0 lanes need g=1's {w0,w1,w4,w5}; g=1 needs g=0's {w2,w3,w6,w7}
  u32 t0 = (u32)__shfl_xor((int)(g ? w[0] : w[2]), 32);
  u32 t1 = (u32)__shfl_xor((int)(g ? w[1] : w[3]), 32);
  u32 t2 = (u32)__shfl_xor((int)(g ? w[4] : w[6]), 32);
  u32 t3 = (u32)__shfl_xor((int)(g ? w[5] : w[7]), 32);
  PW A0, A1;
  A0.w[0] = g ? t0 : w[0];  A0.w[1] = g ? t1 : w[1];
  A0.w[2] = g ? w[2] : t0;  A0.w[3] = g ? w[3] : t1;
  A1.w[0] = g ? t2 : w[4];  A1.w[1] = g ? t3 : w[5];
  A1.w[2] = g ? w[6] : t2;  A1.w[3] = g ? w[7] : t3;
  acc = mfma32(A0.v, L.vA, acc);       // O[q][d]
  acc = mfma32(A1.v, L.vB, acc);
  lacc = mfma32(A0.v, onesb, lacc);    // row sums -> same D rows as acc
  lacc = mfma32(A1.v, onesb, lacc);
}

__global__ __launch_bounds__(256)
void attn_kernel(const bf16_t* __restrict__ q, const bf16_t* __restrict__ k,
                 const bf16_t* __restrict__ vt, const float* __restrict__ bias,
                 bf16_t* __restrict__ out) {
  int tid = threadIdx.x, lane = tid & 63, wid = tid >> 6;
  int l31 = lane & 31, g = lane >> 5;
  // XCD swizzle: 8 q-blocks x 8 bh per XCD
  int x = blockIdx.x & 7, idx = blockIdx.x >> 3;
  int qb = idx & 7;
  int bh = ((idx >> 3) << 3) | x;
  int b = bh >> 3, h = bh & 7;
  int q0 = qb * 128 + wid * 32;
  const bf16_t* qp = q + ((size_t)bh * 1024 + q0 + l31) * 32;
  bf16x8 qf0 = *(const bf16x8*)(qp + g * 8);        // Q[q][d=g*8..], k-half 0
  bf16x8 qf1 = *(const bf16x8*)(qp + 16 + g * 8);   // k-half 1
  const bf16_t* kbase = k + (size_t)bh * 32768;
  const bf16_t* vbase = vt + (size_t)bh * 32768;
  const float* bb = bias + b * 1024;

  bf16x8 onesb;
  #pragma unroll
  for (int e = 0; e < 8; e++) onesb[e] = (bf16_t)1.0f;
  f32x16 acc, lacc;
  #pragma unroll
  for (int r = 0; r < 16; r++) { acc[r] = 0.f; lacc[r] = 0.f; }

  Ld La, Lb;
  ldstep(0, kbase, vbase, bb, l31, g, La);
  for (int kt = 0; kt < 32; kt += 2) {
    ldstep((kt + 1) * 32, kbase, vbase, bb, l31, g, Lb);
    step(La, qf0, qf1, g, acc, lacc, onesb);
    int nx = (kt + 2 < 32) ? (kt + 2) * 32 : 31 * 32;  // clamped tail
    ldstep(nx, kbase, vbase, bb, l31, g, La);
    step(Lb, qf0, qf1, g, acc, lacc, onesb);
  }

  #pragma unroll
  for (int r = 0; r < 16; r++) {
    int row = (r & 3) + 8 * (r >> 2) + 4 * g;
    float o = acc[r] / lacc[r];
    out[((size_t)b * 1024 + q0 + row) * 256 + h * 32 + l31] = (bf16_t)o;
  }
}

// ---------------- launch ----------------
extern "C" void kernel_launch(void* const* d_in, const int* in_sizes, int n_in,
                              void* d_out, int out_size, void* d_ws, size_t ws_size,
                              hipStream_t stream) {
  (void)in_sizes; (void)n_in; (void)out_size; (void)ws_size;
  const float* img0    = (const float*)d_in[0];
  const float* img1    = (const float*)d_in[1];
  const float* mask    = (const float*)d_in[2];
  const float* w_patch = (const float*)d_in[3];
  const float* b_patch = (const float*)d_in[4];
  const float* w_kv    = (const float*)d_in[5];
  const float* b_kv    = (const float*)d_in[6];
  const float* w_qv    = (const float*)d_in[7];
  const float* b_qv    = (const float*)d_in[8];
  const float* w_fc1   = (const float*)d_in[9];
  const float* b_fc1   = (const float*)d_in[10];
  const float* w_fc2   = (const float*)d_in[11];
  const float* b_fc2   = (const float*)d_in[12];
  float* out = (float*)d_out;

  char* ws = (char*)d_ws;
  float*  pe    = (float*)(ws + 0);
  float*  bias  = (float*)(ws + 1048576);
  bf16_t* wpT   = (bf16_t*)(ws + 1081344);
  bf16_t* wkvT  = (bf16_t*)(ws + 1179648);
  bf16_t* wqT   = (bf16_t*)(ws + 1441792);
  bf16_t* wfc1T = (bf16_t*)(ws + 1572864);
  bf16_t* wfc2T = (bf16_t*)(ws + 2097152);
  bf16_t* xp0   = (bf16_t*)(ws + 2621440);
  bf16_t* xp1   = (bf16_t*)(ws + 5767168);
  bf16_t* x0    = (bf16_t*)(ws + 8912896);
  bf16_t* x1    = (bf16_t*)(ws + 13107200);
  bf16_t* kbuf  = (bf16_t*)(ws + 17301504);
  bf16_t* vtbuf = (bf16_t*)(ws + 21495808);
  bf16_t* qbuf  = (bf16_t*)(ws + 25690112);
  bf16_t* aout  = (bf16_t*)(ws + 29884416);
  bf16_t* hbuf  = (bf16_t*)(ws + 34078720);

  prep_all<<<2772, 256, 0, stream>>>(img0, img1, mask, w_patch, w_kv, w_qv, w_fc1, w_fc2,
                                     xp0, xp1, pe, bias, wpT, wkvT, wqT, wfc1T, wfc2T);

  gemm_bt<0, 64><<<dim3(128, 4, 2), 256, 0, stream>>>(xp0, xp1, wpT, nullptr, 8192, 256, 192,
                                                      b_patch, nullptr, pe, x0, x1, nullptr, nullptr);
  gemm_bt<5, 128><<<dim3(128, 6), 256, 0, stream>>>(x0, x1, wkvT, wqT, 8192, 512, 256,
                                                    b_kv, b_qv, nullptr, kbuf, vtbuf, qbuf, nullptr);

  attn_kernel<<<512, 256, 0, stream>>>(qbuf, kbuf, vtbuf, bias, aout);

  gemm_bt<3, 128><<<dim3(128, 8), 256, 0, stream>>>(aout, nullptr, wfc1T, nullptr, 8192, 1024, 256,
                                                    b_fc1, nullptr, nullptr, hbuf, nullptr, nullptr, nullptr);
  gemm_bt<4, 64><<<dim3(128, 4), 256, 0, stream>>>(hbuf, nullptr, wfc2T, nullptr, 8192, 256, 1024,
                                                   b_fc2, nullptr, nullptr, nullptr, nullptr, nullptr, out);
}

// Round 5
// 122.877 us; speedup vs baseline: 1.1805x; 1.0271x over previous
//
#include <hip/hip_runtime.h>
#include <cstdint>
#include <cstddef>

typedef __bf16 bf16_t;
typedef uint32_t u32;
typedef __bf16 bf16x4 __attribute__((ext_vector_type(4)));
typedef __bf16 bf16x8 __attribute__((ext_vector_type(8)));
typedef float f32x4 __attribute__((ext_vector_type(4)));
typedef float f32x16 __attribute__((ext_vector_type(16)));

__device__ __forceinline__ void gload_lds16(const bf16_t* g, bf16_t* l) {
  __builtin_amdgcn_global_load_lds((const __attribute__((address_space(1))) void*)g,
                                   (__attribute__((address_space(3))) void*)l,
                                   16, 0, 0);
}

__device__ __forceinline__ f32x4 mfma16(bf16x8 a, bf16x8 b, f32x4 c) {
  return __builtin_amdgcn_mfma_f32_16x16x32_bf16(a, b, c, 0, 0, 0);
}
__device__ __forceinline__ f32x16 mfma32(bf16x8 a, bf16x8 b, f32x16 c) {
  return __builtin_amdgcn_mfma_f32_32x32x16_bf16(a, b, c, 0, 0, 0);
}

#define LOG2E 1.4426950408889634f

// ---------------- fused prep ----------------
__global__ __launch_bounds__(256)
void prep_all(const float* __restrict__ img0, const float* __restrict__ img1,
              const float* __restrict__ mask,
              const float* __restrict__ wp, const float* __restrict__ wkv,
              const float* __restrict__ wqv, const float* __restrict__ wfc1,
              const float* __restrict__ wfc2,
              bf16_t* __restrict__ xp0, bf16_t* __restrict__ xp1,
              float* __restrict__ pe, float* __restrict__ bias,
              bf16_t* __restrict__ wpT, bf16_t* __restrict__ wkvT,
              bf16_t* __restrict__ wqT, bf16_t* __restrict__ wfc1T,
              bf16_t* __restrict__ wfc2T) {
  __shared__ float tl[64 * 65];
  int bid = blockIdx.x, tid = threadIdx.x;
  if (bid < 1536) {
    int imgsel = bid >= 768;
    int t = (bid - (imgsel ? 768 : 0)) * 256 + tid;
    const float* img = imgsel ? img1 : img0;
    bf16_t* xp = imgsel ? xp1 : xp0;
    int wpp = t & 31, p1 = (t >> 5) & 7, hp = (t >> 8) & 31, rest = t >> 13;
    int b = rest / 3, c = rest - b * 3;
    const float* src = img + (((size_t)(b * 3 + c) * 256 + hp * 8 + p1) * 256 + wpp * 8);
    float4 v0 = *(const float4*)src;
    float4 v1 = *(const float4*)(src + 4);
    int row = b * 1024 + hp * 32 + wpp;
    bf16_t* dst = xp + (size_t)row * 192 + p1 * 24 + c;
    dst[0]  = (bf16_t)v0.x; dst[3]  = (bf16_t)v0.y; dst[6]  = (bf16_t)v0.z; dst[9]  = (bf16_t)v0.w;
    dst[12] = (bf16_t)v1.x; dst[15] = (bf16_t)v1.y; dst[18] = (bf16_t)v1.z; dst[21] = (bf16_t)v1.w;
  } else if (bid < 2560) {
    int t = bid - 1536, c = tid;
    int i2 = c & ~1;
    float div = expf((float)i2 * (-9.210340371976184f / 256.0f));
    float arg = (float)t * div;
    pe[t * 256 + c] = (c & 1) ? cosf(arg) : sinf(arg);
  } else if (bid < 2592) {
    int g = (bid - 2560) * 256 + tid;   // 8192
    int b = g >> 10, t = g & 1023, hp = t >> 5, wpp = t & 31;
    const float* mp = mask + ((size_t)b * 256 + hp * 8) * 256 + wpp * 8;
    float s = 0.f;
    #pragma unroll
    for (int p1 = 0; p1 < 8; p1++) {
      float4 a = *(const float4*)(mp + p1 * 256);
      float4 c = *(const float4*)(mp + p1 * 256 + 4);
      s += a.x + a.y + a.z + a.w + c.x + c.y + c.z + c.w;
    }
    bias[g] = (s > 0.f) ? 0.f : (-100.f * LOG2E);   // log2-domain bias
  } else {
    int i = bid - 2592;
    const float* src; bf16_t* dst; int srcN, dstK, NT;
    if (i >= 172) {                  // zero-pad wfc2T rows 192..255
      int j = i - 172;
      bf16_t* p = wfc2T + 192 * 1024 + j * 8192 + tid * 32;
      bf16x8 z;
      #pragma unroll
      for (int e = 0; e < 8; e++) z[e] = (bf16_t)0.0f;
      *(bf16x8*)(p) = z; *(bf16x8*)(p + 8) = z;
      *(bf16x8*)(p + 16) = z; *(bf16x8*)(p + 24) = z;
      return;
    }
    if (i < 12)       { src = wp;   dst = wpT;   srcN = 256;  dstK = 192;  NT = 4; }
    else if (i < 44)  { i -= 12;  src = wkv;  dst = wkvT;  srcN = 512;  dstK = 256;  NT = 8; }
    else if (i < 60)  { i -= 44;  src = wqv;  dst = wqT;   srcN = 512;  dstK = 256;  NT = 4; }
    else if (i < 124) { i -= 60;  src = wfc1; dst = wfc1T; srcN = 1024; dstK = 256;  NT = 16; }
    else              { i -= 124; src = wfc2; dst = wfc2T; srcN = 192;  dstK = 1024; NT = 3; }
    int kt = i / NT, nt = i - kt * NT;
    #pragma unroll
    for (int j = 0; j < 4; j++) {
      int r = (tid >> 4) + 16 * j, c = (tid & 15) * 4;
      float4 v = *(const float4*)(src + (size_t)(kt * 64 + r) * srcN + nt * 64 + c);
      tl[r * 65 + c] = v.x; tl[r * 65 + c + 1] = v.y;
      tl[r * 65 + c + 2] = v.z; tl[r * 65 + c + 3] = v.w;
    }
    __syncthreads();
    #pragma unroll
    for (int j = 0; j < 16; j++) {
      int flat = tid + 256 * j;
      int n_l = flat >> 6, k_l = flat & 63;
      dst[(size_t)(nt * 64 + n_l) * dstK + kt * 64 + k_l] = (bf16_t)tl[k_l * 65 + n_l];
    }
  }
}

// ---------------- generic GEMM: C = A(MxK) * Bt(NxK)^T ----------------
template<int EPI, int BN>
__global__ __launch_bounds__(256)
void gemm_bt(const bf16_t* __restrict__ A_, const bf16_t* __restrict__ A2,
             const bf16_t* __restrict__ Bt_, const bf16_t* __restrict__ Bt2,
             int M, int N, int K,
             const float* __restrict__ bias_, const float* __restrict__ bias2,
             const float* __restrict__ pe,
             bf16_t* __restrict__ out_b, bf16_t* __restrict__ out_b2,
             bf16_t* __restrict__ out_b3, float* __restrict__ out_f) {
  constexpr int NF = BN / 32;
  __shared__ bf16_t alds[4 * 64 * 8];
  __shared__ bf16_t blds[4 * BN * 8];
  const int tid = threadIdx.x;
  const int lane = tid & 63, wid = tid >> 6;
  const int ln15 = lane & 15, hi = lane >> 4;
  const int brow = blockIdx.x * 64;
  int bcol = blockIdx.y * BN;
  const bf16_t* A = A_;
  const bf16_t* Bt = Bt_;
  const float* bias = bias_;
  bool qpart = false;
  if (EPI == 0 && blockIdx.z) A = A2;
  if (EPI == 5 && blockIdx.y >= 4) {
    qpart = true; A = A2; Bt = Bt2; bias = bias2; bcol -= 512;
  }
  const int wr = wid >> 1, wc = wid & 1;

  f32x4 acc[2][NF];
  #pragma unroll
  for (int m = 0; m < 2; m++)
    #pragma unroll
    for (int n = 0; n < NF; n++) acc[m][n] = (f32x4){0.f, 0.f, 0.f, 0.f};

  for (int k0 = 0; k0 < K; k0 += 32) {
    {
      int c = tid; int row = c & 63; int kb = c >> 6;
      const bf16_t* g = A + (size_t)(brow + row) * K + k0 + kb * 8;
      gload_lds16(g, &alds[(wid * 64) * 8]);
    }
    #pragma unroll
    for (int s = 0; s < BN / 64; s++) {
      int c = tid + s * 256; int row = c & (BN - 1); int kb = c / BN;
      const bf16_t* g = Bt + (size_t)(bcol + row) * K + k0 + kb * 8;
      gload_lds16(g, &blds[(wid * 64 + s * 256) * 8]);
    }
    __syncthreads();
    bf16x8 af[2], bfr[NF];
    #pragma unroll
    for (int m = 0; m < 2; m++)
      af[m] = *(const bf16x8*)&alds[(hi * 64 + wr * 32 + m * 16 + ln15) * 8];
    #pragma unroll
    for (int n = 0; n < NF; n++)
      bfr[n] = *(const bf16x8*)&blds[(hi * BN + wc * (BN / 2) + n * 16 + ln15) * 8];
    #pragma unroll
    for (int m = 0; m < 2; m++)
      #pragma unroll
      for (int n = 0; n < NF; n++)
        acc[m][n] = mfma16(af[m], bfr[n], acc[m][n]);
    __syncthreads();
  }

  #pragma unroll
  for (int m = 0; m < 2; m++) {
    #pragma unroll
    for (int n = 0; n < NF; n++) {
      #pragma unroll
      for (int r = 0; r < 4; r++) {
        int grow = brow + wr * 32 + m * 16 + hi * 4 + r;
        int gcol = bcol + wc * (BN / 2) + n * 16 + ln15;
        float v = acc[m][n][r];
        if (EPI == 0) {
          v += bias[gcol] + pe[(grow & 1023) * 256 + gcol];
          bf16_t* outx = blockIdx.z ? out_b2 : out_b;
          outx[(size_t)grow * N + gcol] = (bf16_t)v;
        } else if (EPI == 5) {
          v += bias[gcol];
          int b = grow >> 10, t = grow & 1023;
          if (!qpart) {
            if (gcol < 256) {
              int h = gcol >> 5, d = gcol & 31;
              out_b[(((size_t)(b * 8 + h) * 1024 + t) << 5) + d] = (bf16_t)v;
            } else {
              int c2 = gcol - 256; int h = c2 >> 5, d = c2 & 31;
              out_b2[(((size_t)(b * 8 + h) * 32 + d) << 10) + t] = (bf16_t)v;
            }
          } else {
            v *= (0.17677669529663687f * LOG2E);   // 1/sqrt(32) * log2(e)
            int h = gcol >> 5, d = gcol & 31;
            out_b3[(((size_t)(b * 8 + h) * 1024 + t) << 5) + d] = (bf16_t)v;
          }
        } else if (EPI == 3) {
          v += bias[gcol];
          float gg = 0.5f * v * (1.0f + erff(v * 0.7071067811865476f));
          out_b[(size_t)grow * N + gcol] = (bf16_t)gg;
        } else if (EPI == 4) {
          if (gcol < 192) {
            v += bias[gcol];
            int b = grow >> 10, t = grow & 1023;
            int hp = t >> 5, wpp = t & 31;
            int p = gcol / 3; int c = gcol - p * 3;
            int p1 = p >> 3, p2 = p & 7;
            out_f[(((size_t)(b * 3 + c) * 256 + hp * 8 + p1) * 256) + wpp * 8 + p2] = v;
          }
        }
      }
    }
  }
}

// ---------------- attention: 32x32 MFMA, in-register P, 4-way split-K ----------------
union PW { u32 w[4]; bf16x8 v; };

__device__ __forceinline__ u32 pkbf(float a, float b) {
  union { bf16_t h[2]; u32 w; } u;
  u.h[0] = (bf16_t)a; u.h[1] = (bf16_t)b;
  return u.w;
}

// swap halves: after call a={a.lo,b.lo}, b={a.hi,b.hi}
__device__ __forceinline__ void pl32swap(u32& a, u32& b) {
  asm volatile("v_permlane32_swap_b32 %0, %1" : "+v"(a), "+v"(b));
}

__global__ __launch_bounds__(256, 4)
void attn_kernel(const bf16_t* __restrict__ q, const bf16_t* __restrict__ k,
                 const bf16_t* __restrict__ vt, const float* __restrict__ bias,
                 bf16_t* __restrict__ out) {
  __shared__ float OL[4][32][34];   // per-wave partial O [q][d]
  __shared__ float LS[4][64];       // per-wave per-lane partial l (q = lane&31)
  int tid = threadIdx.x, lane = tid & 63, wid = tid >> 6;
  int l31 = lane & 31, g = lane >> 5;
  // XCD swizzle: bid&7 selects XCD; all 32 blocks of one bh share an XCD
  int x = blockIdx.x & 7;
  int bh = (((blockIdx.x >> 3) & 7) << 3) | x;
  int qt = blockIdx.x >> 6;                     // 0..31
  int b = bh >> 3, h = bh & 7;
  int q0 = qt * 32;
  const bf16_t* qp = q + ((size_t)bh * 1024 + q0 + l31) * 32;
  bf16x8 qf0 = *(const bf16x8*)(qp + g * 8);
  bf16x8 qf1 = *(const bf16x8*)(qp + 16 + g * 8);
  const bf16_t* kbase = k + (size_t)bh * 32768;
  const bf16_t* vbase = vt + (size_t)bh * 32768;
  const float* bb = bias + b * 1024;

  f32x16 acc;
  #pragma unroll
  for (int r = 0; r < 16; r++) acc[r] = 0.f;
  float lsum = 0.f;

  #pragma unroll
  for (int kt = 0; kt < 8; kt++) {
    int k0 = (wid * 8 + kt) * 32;               // this wave's key range
    bf16x8 kA = *(const bf16x8*)(kbase + (size_t)(k0 + l31) * 32 + g * 8);
    bf16x8 kB = *(const bf16x8*)(kbase + (size_t)(k0 + l31) * 32 + 16 + g * 8);
    bf16x8 vA = *(const bf16x8*)(vbase + (size_t)l31 * 1024 + k0 + g * 8);
    bf16x8 vB = *(const bf16x8*)(vbase + (size_t)l31 * 1024 + k0 + 16 + g * 8);
    f32x4 c0 = *(const f32x4*)(bb + k0 + 4 * g);
    f32x4 c1 = *(const f32x4*)(bb + k0 + 8 + 4 * g);
    f32x4 c2 = *(const f32x4*)(bb + k0 + 16 + 4 * g);
    f32x4 c3 = *(const f32x4*)(bb + k0 + 24 + 4 * g);
    f32x16 S;
    S[0] = c0[0]; S[1] = c0[1]; S[2] = c0[2]; S[3] = c0[3];
    S[4] = c1[0]; S[5] = c1[1]; S[6] = c1[2]; S[7] = c1[3];
    S[8] = c2[0]; S[9] = c2[1]; S[10] = c2[2]; S[11] = c2[3];
    S[12] = c3[0]; S[13] = c3[1]; S[14] = c3[2]; S[15] = c3[3];
    S = mfma32(kA, qf0, S);            // S^T[key][q], log2 domain, bias as C
    S = mfma32(kB, qf1, S);
    float p[16];
    #pragma unroll
    for (int r = 0; r < 16; r++) p[r] = exp2f(S[r]);
    lsum += (((p[0] + p[1]) + (p[2] + p[3])) + ((p[4] + p[5]) + (p[6] + p[7]))) +
            (((p[8] + p[9]) + (p[10] + p[11])) + ((p[12] + p[13]) + (p[14] + p[15])));
    u32 w[8];
    #pragma unroll
    for (int j = 0; j < 8; j++) w[j] = pkbf(p[2 * j], p[2 * j + 1]);
    // half-exchange via permlane32_swap (same movement as verified shfl version)
    u32 xa = w[2], ya = w[0]; pl32swap(xa, ya);
    u32 xb = w[3], yb = w[1]; pl32swap(xb, yb);
    u32 xc = w[6], yc = w[4]; pl32swap(xc, yc);
    u32 xd = w[7], yd = w[5]; pl32swap(xd, yd);
    PW A0, A1;
    A0.w[0] = g ? xa : w[0];  A0.w[2] = g ? w[2] : ya;
    A0.w[1] = g ? xb : w[1];  A0.w[3] = g ? w[3] : yb;
    A1.w[0] = g ? xc : w[4];  A1.w[2] = g ? w[6] : yc;
    A1.w[1] = g ? xd : w[5];  A1.w[3] = g ? w[7] : yd;
    acc = mfma32(A0.v, vA, acc);       // O[q][d] partial
    acc = mfma32(A1.v, vB, acc);
  }

  // write partials to LDS
  #pragma unroll
  for (int r = 0; r < 16; r++) {
    int row = (r & 3) + 8 * (r >> 2) + 4 * g;
    OL[wid][row][l31] = acc[r];
  }
  LS[wid][lane] = lsum;
  __syncthreads();

  // combine: thread t -> q row (t>>3), 4 d-cols
  int qq = tid >> 3, d0 = (tid & 7) * 4;
  float l = 0.f;
  #pragma unroll
  for (int w2 = 0; w2 < 4; w2++) l += LS[w2][qq] + LS[w2][32 + qq];
  float o0 = 0.f, o1 = 0.f, o2 = 0.f, o3 = 0.f;
  #pragma unroll
  for (int w2 = 0; w2 < 4; w2++) {
    o0 += OL[w2][qq][d0];     o1 += OL[w2][qq][d0 + 1];
    o2 += OL[w2][qq][d0 + 2]; o3 += OL[w2][qq][d0 + 3];
  }
  float linv = 1.f / l;
  bf16x4 ov;
  ov[0] = (bf16_t)(o0 * linv); ov[1] = (bf16_t)(o1 * linv);
  ov[2] = (bf16_t)(o2 * linv); ov[3] = (bf16_t)(o3 * linv);
  *(bf16x4*)(out + ((size_t)b * 1024 + q0 + qq) * 256 + h * 32 + d0) = ov;
}

// ---------------- launch ----------------
extern "C" void kernel_launch(void* const* d_in, const int* in_sizes, int n_in,
                              void* d_out, int out_size, void* d_ws, size_t ws_size,
                              hipStream_t stream) {
  (void)in_sizes; (void)n_in; (void)out_size; (void)ws_size;
  const float* img0    = (const float*)d_in[0];
  const float* img1    = (const float*)d_in[1];
  const float* mask    = (const float*)d_in[2];
  const float* w_patch = (const float*)d_in[3];
  const float* b_patch = (const float*)d_in[4];
  const float* w_kv    = (const float*)d_in[5];
  const float* b_kv    = (const float*)d_in[6];
  const float* w_qv    = (const float*)d_in[7];
  const float* b_qv    = (const float*)d_in[8];
  const float* w_fc1   = (const float*)d_in[9];
  const float* b_fc1   = (const float*)d_in[10];
  const float* w_fc2   = (const float*)d_in[11];
  const float* b_fc2   = (const float*)d_in[12];
  float* out = (float*)d_out;

  char* ws = (char*)d_ws;
  float*  pe    = (float*)(ws + 0);
  float*  bias  = (float*)(ws + 1048576);
  bf16_t* wpT   = (bf16_t*)(ws + 1081344);
  bf16_t* wkvT  = (bf16_t*)(ws + 1179648);
  bf16_t* wqT   = (bf16_t*)(ws + 1441792);
  bf16_t* wfc1T = (bf16_t*)(ws + 1572864);
  bf16_t* wfc2T = (bf16_t*)(ws + 2097152);
  bf16_t* xp0   = (bf16_t*)(ws + 2621440);
  bf16_t* xp1   = (bf16_t*)(ws + 5767168);
  bf16_t* x0    = (bf16_t*)(ws + 8912896);
  bf16_t* x1    = (bf16_t*)(ws + 13107200);
  bf16_t* kbuf  = (bf16_t*)(ws + 17301504);
  bf16_t* vtbuf = (bf16_t*)(ws + 21495808);
  bf16_t* qbuf  = (bf16_t*)(ws + 25690112);
  bf16_t* aout  = (bf16_t*)(ws + 29884416);
  bf16_t* hbuf  = (bf16_t*)(ws + 34078720);

  prep_all<<<2772, 256, 0, stream>>>(img0, img1, mask, w_patch, w_kv, w_qv, w_fc1, w_fc2,
                                     xp0, xp1, pe, bias, wpT, wkvT, wqT, wfc1T, wfc2T);

  gemm_bt<0, 64><<<dim3(128, 4, 2), 256, 0, stream>>>(xp0, xp1, wpT, nullptr, 8192, 256, 192,
                                                      b_patch, nullptr, pe, x0, x1, nullptr, nullptr);
  gemm_bt<5, 128><<<dim3(128, 6), 256, 0, stream>>>(x0, x1, wkvT, wqT, 8192, 512, 256,
                                                    b_kv, b_qv, nullptr, kbuf, vtbuf, qbuf, nullptr);

  attn_kernel<<<2048, 256, 0, stream>>>(qbuf, kbuf, vtbuf, bias, aout);

  gemm_bt<3, 128><<<dim3(128, 8), 256, 0, stream>>>(aout, nullptr, wfc1T, nullptr, 8192, 1024, 256,
                                                    b_fc1, nullptr, nullptr, hbuf, nullptr, nullptr, nullptr);
  gemm_bt<4, 64><<<dim3(128, 4), 256, 0, stream>>>(hbuf, nullptr, wfc2T, nullptr, 8192, 256, 1024,
                                                   b_fc2, nullptr, nullptr, nullptr, nullptr, nullptr, out);
}

// Round 6
// 121.862 us; speedup vs baseline: 1.1903x; 1.0083x over previous
//
#include <hip/hip_runtime.h>
#include <cstdint>
#include <cstddef>

typedef __bf16 bf16_t;
typedef uint32_t u32;
typedef __bf16 bf16x4 __attribute__((ext_vector_type(4)));
typedef __bf16 bf16x8 __attribute__((ext_vector_type(8)));
typedef float f32x4 __attribute__((ext_vector_type(4)));
typedef float f32x16 __attribute__((ext_vector_type(16)));

__device__ __forceinline__ void gload_lds16(const bf16_t* g, bf16_t* l) {
  __builtin_amdgcn_global_load_lds((const __attribute__((address_space(1))) void*)g,
                                   (__attribute__((address_space(3))) void*)l,
                                   16, 0, 0);
}

__device__ __forceinline__ f32x4 mfma16(bf16x8 a, bf16x8 b, f32x4 c) {
  return __builtin_amdgcn_mfma_f32_16x16x32_bf16(a, b, c, 0, 0, 0);
}
__device__ __forceinline__ f32x16 mfma32(bf16x8 a, bf16x8 b, f32x16 c) {
  return __builtin_amdgcn_mfma_f32_32x32x16_bf16(a, b, c, 0, 0, 0);
}

#define LOG2E 1.4426950408889634f

// ---------------- fused prep ----------------
__global__ __launch_bounds__(256)
void prep_all(const float* __restrict__ img0, const float* __restrict__ img1,
              const float* __restrict__ mask,
              const float* __restrict__ wp, const float* __restrict__ wkv,
              const float* __restrict__ wqv, const float* __restrict__ wfc1,
              const float* __restrict__ wfc2,
              bf16_t* __restrict__ xp0, bf16_t* __restrict__ xp1,
              float* __restrict__ pe, float* __restrict__ bias,
              bf16_t* __restrict__ wpT, bf16_t* __restrict__ wkvT,
              bf16_t* __restrict__ wqT, bf16_t* __restrict__ wfc1T,
              bf16_t* __restrict__ wfc2T) {
  __shared__ float tl[64 * 65];
  int bid = blockIdx.x, tid = threadIdx.x;
  if (bid < 1536) {
    int imgsel = bid >= 768;
    int t = (bid - (imgsel ? 768 : 0)) * 256 + tid;
    const float* img = imgsel ? img1 : img0;
    bf16_t* xp = imgsel ? xp1 : xp0;
    int wpp = t & 31, p1 = (t >> 5) & 7, hp = (t >> 8) & 31, rest = t >> 13;
    int b = rest / 3, c = rest - b * 3;
    const float* src = img + (((size_t)(b * 3 + c) * 256 + hp * 8 + p1) * 256 + wpp * 8);
    float4 v0 = *(const float4*)src;
    float4 v1 = *(const float4*)(src + 4);
    int row = b * 1024 + hp * 32 + wpp;
    bf16_t* dst = xp + (size_t)row * 192 + p1 * 24 + c;
    dst[0]  = (bf16_t)v0.x; dst[3]  = (bf16_t)v0.y; dst[6]  = (bf16_t)v0.z; dst[9]  = (bf16_t)v0.w;
    dst[12] = (bf16_t)v1.x; dst[15] = (bf16_t)v1.y; dst[18] = (bf16_t)v1.z; dst[21] = (bf16_t)v1.w;
  } else if (bid < 2560) {
    int t = bid - 1536, c = tid;
    int i2 = c & ~1;
    float div = expf((float)i2 * (-9.210340371976184f / 256.0f));
    float arg = (float)t * div;
    pe[t * 256 + c] = (c & 1) ? cosf(arg) : sinf(arg);
  } else if (bid < 2592) {
    int g = (bid - 2560) * 256 + tid;   // 8192
    int b = g >> 10, t = g & 1023, hp = t >> 5, wpp = t & 31;
    const float* mp = mask + ((size_t)b * 256 + hp * 8) * 256 + wpp * 8;
    float s = 0.f;
    #pragma unroll
    for (int p1 = 0; p1 < 8; p1++) {
      float4 a = *(const float4*)(mp + p1 * 256);
      float4 c = *(const float4*)(mp + p1 * 256 + 4);
      s += a.x + a.y + a.z + a.w + c.x + c.y + c.z + c.w;
    }
    bias[g] = (s > 0.f) ? 0.f : (-100.f * LOG2E);   // log2-domain bias
  } else {
    int i = bid - 2592;
    const float* src; bf16_t* dst; int srcN, dstK, NT;
    if (i >= 172) {                  // zero-pad wfc2T rows 192..255
      int j = i - 172;
      bf16_t* p = wfc2T + 192 * 1024 + j * 8192 + tid * 32;
      bf16x8 z;
      #pragma unroll
      for (int e = 0; e < 8; e++) z[e] = (bf16_t)0.0f;
      *(bf16x8*)(p) = z; *(bf16x8*)(p + 8) = z;
      *(bf16x8*)(p + 16) = z; *(bf16x8*)(p + 24) = z;
      return;
    }
    if (i < 12)       { src = wp;   dst = wpT;   srcN = 256;  dstK = 192;  NT = 4; }
    else if (i < 44)  { i -= 12;  src = wkv;  dst = wkvT;  srcN = 512;  dstK = 256;  NT = 8; }
    else if (i < 60)  { i -= 44;  src = wqv;  dst = wqT;   srcN = 512;  dstK = 256;  NT = 4; }
    else if (i < 124) { i -= 60;  src = wfc1; dst = wfc1T; srcN = 1024; dstK = 256;  NT = 16; }
    else              { i -= 124; src = wfc2; dst = wfc2T; srcN = 192;  dstK = 1024; NT = 3; }
    int kt = i / NT, nt = i - kt * NT;
    #pragma unroll
    for (int j = 0; j < 4; j++) {
      int r = (tid >> 4) + 16 * j, c = (tid & 15) * 4;
      float4 v = *(const float4*)(src + (size_t)(kt * 64 + r) * srcN + nt * 64 + c);
      tl[r * 65 + c] = v.x; tl[r * 65 + c + 1] = v.y;
      tl[r * 65 + c + 2] = v.z; tl[r * 65 + c + 3] = v.w;
    }
    __syncthreads();
    #pragma unroll
    for (int j = 0; j < 16; j++) {
      int flat = tid + 256 * j;
      int n_l = flat >> 6, k_l = flat & 63;
      dst[(size_t)(nt * 64 + n_l) * dstK + kt * 64 + k_l] = (bf16_t)tl[k_l * 65 + n_l];
    }
  }
}

// ---------------- generic GEMM: C = A(MxK) * Bt(NxK)^T ----------------
template<int EPI, int BN>
__global__ __launch_bounds__(256)
void gemm_bt(const bf16_t* __restrict__ A_, const bf16_t* __restrict__ A2,
             const bf16_t* __restrict__ Bt_, const bf16_t* __restrict__ Bt2,
             int M, int N, int K,
             const float* __restrict__ bias_, const float* __restrict__ bias2,
             const float* __restrict__ pe,
             bf16_t* __restrict__ out_b, bf16_t* __restrict__ out_b2,
             bf16_t* __restrict__ out_b3, float* __restrict__ out_f) {
  constexpr int NF = BN / 32;
  __shared__ bf16_t alds[4 * 64 * 8];
  __shared__ bf16_t blds[4 * BN * 8];
  const int tid = threadIdx.x;
  const int lane = tid & 63, wid = tid >> 6;
  const int ln15 = lane & 15, hi = lane >> 4;
  const int brow = blockIdx.x * 64;
  int bcol = blockIdx.y * BN;
  const bf16_t* A = A_;
  const bf16_t* Bt = Bt_;
  const float* bias = bias_;
  bool qpart = false;
  if (EPI == 0 && blockIdx.z) A = A2;
  if (EPI == 5 && blockIdx.y >= 4) {
    qpart = true; A = A2; Bt = Bt2; bias = bias2; bcol -= 512;
  }
  const int wr = wid >> 1, wc = wid & 1;

  f32x4 acc[2][NF];
  #pragma unroll
  for (int m = 0; m < 2; m++)
    #pragma unroll
    for (int n = 0; n < NF; n++) acc[m][n] = (f32x4){0.f, 0.f, 0.f, 0.f};

  for (int k0 = 0; k0 < K; k0 += 32) {
    {
      int c = tid; int row = c & 63; int kb = c >> 6;
      const bf16_t* g = A + (size_t)(brow + row) * K + k0 + kb * 8;
      gload_lds16(g, &alds[(wid * 64) * 8]);
    }
    #pragma unroll
    for (int s = 0; s < BN / 64; s++) {
      int c = tid + s * 256; int row = c & (BN - 1); int kb = c / BN;
      const bf16_t* g = Bt + (size_t)(bcol + row) * K + k0 + kb * 8;
      gload_lds16(g, &blds[(wid * 64 + s * 256) * 8]);
    }
    __syncthreads();
    bf16x8 af[2], bfr[NF];
    #pragma unroll
    for (int m = 0; m < 2; m++)
      af[m] = *(const bf16x8*)&alds[(hi * 64 + wr * 32 + m * 16 + ln15) * 8];
    #pragma unroll
    for (int n = 0; n < NF; n++)
      bfr[n] = *(const bf16x8*)&blds[(hi * BN + wc * (BN / 2) + n * 16 + ln15) * 8];
    #pragma unroll
    for (int m = 0; m < 2; m++)
      #pragma unroll
      for (int n = 0; n < NF; n++)
        acc[m][n] = mfma16(af[m], bfr[n], acc[m][n]);
    __syncthreads();
  }

  #pragma unroll
  for (int m = 0; m < 2; m++) {
    #pragma unroll
    for (int n = 0; n < NF; n++) {
      #pragma unroll
      for (int r = 0; r < 4; r++) {
        int grow = brow + wr * 32 + m * 16 + hi * 4 + r;
        int gcol = bcol + wc * (BN / 2) + n * 16 + ln15;
        float v = acc[m][n][r];
        if (EPI == 0) {
          v += bias[gcol] + pe[(grow & 1023) * 256 + gcol];
          bf16_t* outx = blockIdx.z ? out_b2 : out_b;
          outx[(size_t)grow * N + gcol] = (bf16_t)v;
        } else if (EPI == 5) {
          v += bias[gcol];
          int b = grow >> 10, t = grow & 1023;
          if (!qpart) {
            if (gcol < 256) {
              int h = gcol >> 5, d = gcol & 31;
              out_b[(((size_t)(b * 8 + h) * 1024 + t) << 5) + d] = (bf16_t)v;
            } else {
              int c2 = gcol - 256; int h = c2 >> 5, d = c2 & 31;
              out_b2[(((size_t)(b * 8 + h) * 32 + d) << 10) + t] = (bf16_t)v;
            }
          } else {
            v *= (0.17677669529663687f * LOG2E);   // 1/sqrt(32) * log2(e)
            int h = gcol >> 5, d = gcol & 31;
            out_b3[(((size_t)(b * 8 + h) * 1024 + t) << 5) + d] = (bf16_t)v;
          }
        } else if (EPI == 3) {
          v += bias[gcol];
          float gg = 0.5f * v * (1.0f + erff(v * 0.7071067811865476f));
          out_b[(size_t)grow * N + gcol] = (bf16_t)gg;
        } else if (EPI == 4) {
          if (gcol < 192) {
            v += bias[gcol];
            int b = grow >> 10, t = grow & 1023;
            int hp = t >> 5, wpp = t & 31;
            int p = gcol / 3; int c = gcol - p * 3;
            int p1 = p >> 3, p2 = p & 7;
            out_f[(((size_t)(b * 3 + c) * 256 + hp * 8 + p1) * 256) + wpp * 8 + p2] = v;
          }
        }
      }
    }
  }
}

// ---------------- attention: flash-style, LDS-staged K/V, in-register P ----------------
union PW { u32 w[4]; bf16x8 v; };

__device__ __forceinline__ u32 pkbf(float a, float b) {
  union { bf16_t h[2]; u32 w; } u;
  u.h[0] = (bf16_t)a; u.h[1] = (bf16_t)b;
  return u.w;
}

// swap halves: after call a={a.lo,b.lo}, b={a.hi,b.hi}
__device__ __forceinline__ void pl32swap(u32& a, u32& b) {
  asm volatile("v_permlane32_swap_b32 %0, %1" : "+v"(a), "+v"(b));
}

// Stage one 256-key chunk of K and V into LDS (XOR-swizzled 16B slots, lane-linear dest).
// K LDS: [256 rows][4 chunks], slot = row*4 + (c ^ (row&3))  <- global K[key][32d]
// V LDS: [32 rows][32 chunks], slot = row*32 + (c ^ row)     <- global vt[d][1024keys]
__device__ __forceinline__ void stage_kv(const bf16_t* kbase, const bf16_t* vbase,
                                         int ch, bf16_t* kl, bf16_t* vl,
                                         int tid, int wid) {
  #pragma unroll
  for (int p = 0; p < 4; p++) {
    int s = p * 256 + tid;
    int row = s >> 2, cs = (s & 3) ^ (row & 3);
    const bf16_t* src = kbase + (size_t)(ch * 256 + row) * 32 + cs * 8;
    gload_lds16(src, kl + (size_t)(p * 256 + wid * 64) * 8);
  }
  #pragma unroll
  for (int p = 0; p < 4; p++) {
    int s = p * 256 + tid;
    int row = s >> 5, cs = (s & 31) ^ row;
    const bf16_t* src = vbase + (size_t)row * 1024 + ch * 256 + cs * 8;
    gload_lds16(src, vl + (size_t)(p * 256 + wid * 64) * 8);
  }
}

__global__ __launch_bounds__(256, 2)
void attn_kernel(const bf16_t* __restrict__ q, const bf16_t* __restrict__ k,
                 const bf16_t* __restrict__ vt, const float* __restrict__ bias,
                 bf16_t* __restrict__ out) {
  __shared__ bf16_t klds[2][1024 * 8];   // 16 KB per buffer
  __shared__ bf16_t vlds[2][1024 * 8];   // 16 KB per buffer
  __shared__ float LSL[4][32];
  int tid = threadIdx.x, lane = tid & 63, wid = tid >> 6;
  int l31 = lane & 31, g = lane >> 5;
  // XCD swizzle: bid&7 = XCD; all 8 q-tiles of one bh on one XCD
  int x = blockIdx.x & 7, idx = blockIdx.x >> 3;
  int qt = idx & 7;
  int bh = ((idx >> 3) << 3) | x;
  int b = bh >> 3, h = bh & 7;
  int q0 = qt * 128 + wid * 32;
  const bf16_t* qp = q + ((size_t)bh * 1024 + q0 + l31) * 32;
  bf16x8 qf0 = *(const bf16x8*)(qp + g * 8);
  bf16x8 qf1 = *(const bf16x8*)(qp + 16 + g * 8);
  const bf16_t* kbase = k + (size_t)bh * 32768;
  const bf16_t* vbase = vt + (size_t)bh * 32768;
  const float* bb = bias + b * 1024;

  f32x16 acc;
  #pragma unroll
  for (int r = 0; r < 16; r++) acc[r] = 0.f;
  float lsum = 0.f;

  stage_kv(kbase, vbase, 0, klds[0], vlds[0], tid, wid);
  __syncthreads();                       // compiler drains vmcnt before barrier

  int cur = 0;
  for (int ch = 0; ch < 4; ch++) {
    if (ch < 3) stage_kv(kbase, vbase, ch + 1, klds[cur ^ 1], vlds[cur ^ 1], tid, wid);
    const bf16_t* kl = klds[cur];
    const bf16_t* vl = vlds[cur];
    #pragma unroll
    for (int kt = 0; kt < 8; kt++) {
      int row0 = kt * 32 + l31;
      bf16x8 kA = *(const bf16x8*)(kl + (size_t)(row0 * 4 + (g ^ (row0 & 3))) * 8);
      bf16x8 kB = *(const bf16x8*)(kl + (size_t)(row0 * 4 + ((2 + g) ^ (row0 & 3))) * 8);
      bf16x8 vA = *(const bf16x8*)(vl + (size_t)(l31 * 32 + ((4 * kt + g) ^ l31)) * 8);
      bf16x8 vB = *(const bf16x8*)(vl + (size_t)(l31 * 32 + ((4 * kt + 2 + g) ^ l31)) * 8);
      int K0 = ch * 256 + kt * 32;
      f32x4 c0 = *(const f32x4*)(bb + K0 + 4 * g);
      f32x4 c1 = *(const f32x4*)(bb + K0 + 8 + 4 * g);
      f32x4 c2 = *(const f32x4*)(bb + K0 + 16 + 4 * g);
      f32x4 c3 = *(const f32x4*)(bb + K0 + 24 + 4 * g);
      f32x16 S;
      S[0] = c0[0]; S[1] = c0[1]; S[2] = c0[2]; S[3] = c0[3];
      S[4] = c1[0]; S[5] = c1[1]; S[6] = c1[2]; S[7] = c1[3];
      S[8] = c2[0]; S[9] = c2[1]; S[10] = c2[2]; S[11] = c2[3];
      S[12] = c3[0]; S[13] = c3[1]; S[14] = c3[2]; S[15] = c3[3];
      S = mfma32(kA, qf0, S);            // S^T[key][q], log2 domain, bias as C
      S = mfma32(kB, qf1, S);
      float p[16];
      #pragma unroll
      for (int r = 0; r < 16; r++) p[r] = exp2f(S[r]);
      lsum += (((p[0] + p[1]) + (p[2] + p[3])) + ((p[4] + p[5]) + (p[6] + p[7]))) +
              (((p[8] + p[9]) + (p[10] + p[11])) + ((p[12] + p[13]) + (p[14] + p[15])));
      u32 w[8];
      #pragma unroll
      for (int j = 0; j < 8; j++) w[j] = pkbf(p[2 * j], p[2 * j + 1]);
      u32 xa = w[2], ya = w[0]; pl32swap(xa, ya);
      u32 xb = w[3], yb = w[1]; pl32swap(xb, yb);
      u32 xc = w[6], yc = w[4]; pl32swap(xc, yc);
      u32 xd = w[7], yd = w[5]; pl32swap(xd, yd);
      PW A0, A1;
      A0.w[0] = g ? xa : w[0];  A0.w[2] = g ? w[2] : ya;
      A0.w[1] = g ? xb : w[1];  A0.w[3] = g ? w[3] : yb;
      A1.w[0] = g ? xc : w[4];  A1.w[2] = g ? w[6] : yc;
      A1.w[1] = g ? xd : w[5];  A1.w[3] = g ? w[7] : yd;
      acc = mfma32(A0.v, vA, acc);       // O[q][d]
      acc = mfma32(A1.v, vB, acc);
    }
    __syncthreads();                     // drains staged loads + readers done
    cur ^= 1;
  }

  // l: lane(l31,g) partial -> total per q=l31
  lsum += __shfl_xor(lsum, 32);
  LSL[wid][l31] = lsum;                  // both halves write identical value
  #pragma unroll
  for (int r = 0; r < 16; r++) {
    int row = (r & 3) + 8 * (r >> 2) + 4 * g;
    float linv = 1.f / LSL[wid][row];
    out[((size_t)b * 1024 + q0 + row) * 256 + h * 32 + l31] = (bf16_t)(acc[r] * linv);
  }
}

// ---------------- launch ----------------
extern "C" void kernel_launch(void* const* d_in, const int* in_sizes, int n_in,
                              void* d_out, int out_size, void* d_ws, size_t ws_size,
                              hipStream_t stream) {
  (void)in_sizes; (void)n_in; (void)out_size; (void)ws_size;
  const float* img0    = (const float*)d_in[0];
  const float* img1    = (const float*)d_in[1];
  const float* mask    = (const float*)d_in[2];
  const float* w_patch = (const float*)d_in[3];
  const float* b_patch = (const float*)d_in[4];
  const float* w_kv    = (const float*)d_in[5];
  const float* b_kv    = (const float*)d_in[6];
  const float* w_qv    = (const float*)d_in[7];
  const float* b_qv    = (const float*)d_in[8];
  const float* w_fc1   = (const float*)d_in[9];
  const float* b_fc1   = (const float*)d_in[10];
  const float* w_fc2   = (const float*)d_in[11];
  const float* b_fc2   = (const float*)d_in[12];
  float* out = (float*)d_out;

  char* ws = (char*)d_ws;
  float*  pe    = (float*)(ws + 0);
  float*  bias  = (float*)(ws + 1048576);
  bf16_t* wpT   = (bf16_t*)(ws + 1081344);
  bf16_t* wkvT  = (bf16_t*)(ws + 1179648);
  bf16_t* wqT   = (bf16_t*)(ws + 1441792);
  bf16_t* wfc1T = (bf16_t*)(ws + 1572864);
  bf16_t* wfc2T = (bf16_t*)(ws + 2097152);
  bf16_t* xp0   = (bf16_t*)(ws + 2621440);
  bf16_t* xp1   = (bf16_t*)(ws + 5767168);
  bf16_t* x0    = (bf16_t*)(ws + 8912896);
  bf16_t* x1    = (bf16_t*)(ws + 13107200);
  bf16_t* kbuf  = (bf16_t*)(ws + 17301504);
  bf16_t* vtbuf = (bf16_t*)(ws + 21495808);
  bf16_t* qbuf  = (bf16_t*)(ws + 25690112);
  bf16_t* aout  = (bf16_t*)(ws + 29884416);
  bf16_t* hbuf  = (bf16_t*)(ws + 34078720);

  prep_all<<<2772, 256, 0, stream>>>(img0, img1, mask, w_patch, w_kv, w_qv, w_fc1, w_fc2,
                                     xp0, xp1, pe, bias, wpT, wkvT, wqT, wfc1T, wfc2T);

  gemm_bt<0, 64><<<dim3(128, 4, 2), 256, 0, stream>>>(xp0, xp1, wpT, nullptr, 8192, 256, 192,
                                                      b_patch, nullptr, pe, x0, x1, nullptr, nullptr);
  gemm_bt<5, 128><<<dim3(128, 6), 256, 0, stream>>>(x0, x1, wkvT, wqT, 8192, 512, 256,
                                                    b_kv, b_qv, nullptr, kbuf, vtbuf, qbuf, nullptr);

  attn_kernel<<<512, 256, 0, stream>>>(qbuf, kbuf, vtbuf, bias, aout);

  gemm_bt<3, 128><<<dim3(128, 8), 256, 0, stream>>>(aout, nullptr, wfc1T, nullptr, 8192, 1024, 256,
                                                    b_fc1, nullptr, nullptr, hbuf, nullptr, nullptr, nullptr);
  gemm_bt<4, 64><<<dim3(128, 4), 256, 0, stream>>>(hbuf, nullptr, wfc2T, nullptr, 8192, 256, 1024,
                                                   b_fc2, nullptr, nullptr, nullptr, nullptr, nullptr, out);
}